// Round 4
// baseline (45690.417 us; speedup 1.0000x reference)
//
#include <hip/hip_runtime.h>
#include <cstdint>

#define BATCH 4096
#define LATENT 128
#define RNN 512
#define CODE 512
#define DISC 64
#define NSEG 64
#define UNPACK_COLS 130  // LATENT + INPUT

// ------------- threefry2x32, JAX partitionable mode, key = (0, 42) -----------
// bits(n) = w0 ^ w1 where (w0,w1) = threefry2x32(key=(0,42), counter=(0, n)).
__device__ __forceinline__ uint32_t rotl32(uint32_t x, uint32_t r) {
  return (x << r) | (x >> (32u - r));
}

__device__ __forceinline__ uint32_t threefry_bits(uint32_t n) {
  const uint32_t k0 = 0u, k1 = 42u;
  const uint32_t ks2 = k0 ^ k1 ^ 0x1BD11BDAu;
  uint32_t x0 = 0u, x1 = n;          // counter = (hi32, lo32) of flat index
  x0 += k0; x1 += k1;
#define TF_ROUND(r) { x0 += x1; x1 = rotl32(x1, r); x1 ^= x0; }
  TF_ROUND(13) TF_ROUND(15) TF_ROUND(26) TF_ROUND(6)
  x0 += k1;  x1 += ks2 + 1u;
  TF_ROUND(17) TF_ROUND(29) TF_ROUND(16) TF_ROUND(24)
  x0 += ks2; x1 += k0 + 2u;
  TF_ROUND(13) TF_ROUND(15) TF_ROUND(26) TF_ROUND(6)
  x0 += k0;  x1 += k1 + 3u;
  TF_ROUND(17) TF_ROUND(29) TF_ROUND(16) TF_ROUND(24)
  x0 += k1;  x1 += ks2 + 4u;
  TF_ROUND(13) TF_ROUND(15) TF_ROUND(26) TF_ROUND(6)
  x0 += ks2; x1 += k0 + 5u;
#undef TF_ROUND
  return x0 ^ x1;
}

__device__ __forceinline__ float sigmoidf_(float v) {
  return 1.0f / (1.0f + expf(-v));
}

// ---------------- base = latent @ W_unpack[:, :128]^T + b_unpack --------------
__global__ __launch_bounds__(256) void base_kernel(
    const float* __restrict__ latent, const float* __restrict__ Wu,
    const float* __restrict__ bu, float* __restrict__ base) {
  __shared__ float lrow[LATENT];
  const int b = blockIdx.x;
  if (threadIdx.x < LATENT) lrow[threadIdx.x] = latent[b * LATENT + threadIdx.x];
  __syncthreads();
  for (int n = threadIdx.x; n < CODE; n += 256) {
    const float* wr = Wu + (size_t)n * UNPACK_COLS;
    float acc = 0.f;
#pragma unroll 8
    for (int k = 0; k < LATENT; ++k) acc += lrow[k] * wr[k];
    base[(size_t)b * CODE + n] = acc + bu[n];
  }
}

// ---------------- x = tanh(base + angle * W_unpack[:, 128]) -------------------
__global__ __launch_bounds__(256) void x_kernel(
    const float* __restrict__ base, const float* __restrict__ angle,
    const float* __restrict__ Wu, float* __restrict__ xo) {
  const int idx = blockIdx.x * 256 + threadIdx.x;
  const int b = idx >> 9;
  const int n = idx & 511;
  xo[idx] = tanhf(base[idx] + angle[b] * Wu[(size_t)n * UNPACK_COLS + 128]);
}

// ----- fused: gates = A1@W1^T + A2@W2^T + b1 + b2 ; (h,c) = LSTM(gates, c) ----
// Reg-staged pipeline: loads for K-step k+1 are issued before compute of step
// k, so global latency hides under the 2048-FMA compute phase.  Single LDS
// buffer, 2 barriers per K-step.  K-major LDS with XOR swizzle
// col = row ^ (((k>>2)&7)<<3): stores 2-way (free), reads conflict-optimal.
#define BM 128
#define BN 128
#define BK 32
#define KSTEPS 32  // 2 segs * (512/32)

__global__ __launch_bounds__(256) void gemm_lstm(
    const float* __restrict__ A1, const float* __restrict__ W1,
    const float* __restrict__ A2, const float* __restrict__ W2,
    const float* __restrict__ b1, const float* __restrict__ b2,
    float* __restrict__ c_io, float* __restrict__ h_out) {
  const int K = RNN;
  __shared__ __align__(16) float As[BK][BM];
  __shared__ __align__(16) float Ws[BK][BN];
  const int tid = threadIdx.x;
  const int tx = tid & 15, ty = tid >> 4;
  const int bx = blockIdx.x;            // 16 N-tiles of (4 gates x 32 cols)
  const int rowBase = blockIdx.y * BM;
  const int lrow = tid >> 2;            // 0..63
  const int q = tid & 3;
  const int lk = q * 4;                 // k sub-offset 0,4,8,12 (+16 for kh=1)

  float acc[8][8];
#pragma unroll
  for (int i = 0; i < 8; ++i)
#pragma unroll
    for (int j = 0; j < 8; ++j) acc[i][j] = 0.f;

  float4 ra[2][2], rw[2][2];  // [r][kh] staging registers

  // W row index for this lane (gate-tiled N mapping), per r
  int wn[2];
#pragma unroll
  for (int r = 0; r < 2; ++r) {
    const int rr = lrow + r * 64;
    wn[r] = ((rr >> 5) * RNN) + (bx << 5) + (rr & 31);
  }

#define ISSUE_LOADS(step)                                                      \
  {                                                                            \
    const int seg_ = (step) >> 4;                                              \
    const int k0_ = ((step) & 15) * BK;                                        \
    const float* __restrict__ A_ = seg_ ? A2 : A1;                             \
    const float* __restrict__ W_ = seg_ ? W2 : W1;                             \
    _Pragma("unroll") for (int r = 0; r < 2; ++r) {                            \
      const int rr_ = lrow + r * 64;                                           \
      _Pragma("unroll") for (int kh = 0; kh < 2; ++kh) {                       \
        ra[r][kh] = *(const float4*)&A_[(size_t)(rowBase + rr_) * K + k0_ +    \
                                        kh * 16 + lk];                         \
        rw[r][kh] = *(const float4*)&W_[(size_t)wn[r] * K + k0_ + kh * 16 +    \
                                        lk];                                   \
      }                                                                        \
    }                                                                          \
  }

  ISSUE_LOADS(0)

  for (int step = 0; step < KSTEPS; ++step) {
    __syncthreads();  // everyone done reading LDS from previous compute
    // regs -> LDS (transposed to k-major, swizzled)
#pragma unroll
    for (int r = 0; r < 2; ++r) {
      const int rr = lrow + r * 64;
#pragma unroll
      for (int kh = 0; kh < 2; ++kh) {
        const int kq = q + kh * 4;        // (k>>2) quad index 0..7
        const int cc = rr ^ (kq << 3);
        const int kb = kh * 16 + lk;
        As[kb + 0][cc] = ra[r][kh].x; As[kb + 1][cc] = ra[r][kh].y;
        As[kb + 2][cc] = ra[r][kh].z; As[kb + 3][cc] = ra[r][kh].w;
        Ws[kb + 0][cc] = rw[r][kh].x; Ws[kb + 1][cc] = rw[r][kh].y;
        Ws[kb + 2][cc] = rw[r][kh].z; Ws[kb + 3][cc] = rw[r][kh].w;
      }
    }
    __syncthreads();
    if (step + 1 < KSTEPS) ISSUE_LOADS(step + 1)  // in flight under compute
#pragma unroll
    for (int kk = 0; kk < BK; ++kk) {
      const int swk = ((kk >> 2) & 7) << 3;
      const float4 a0 = *(const float4*)&As[kk][(ty * 4) ^ swk];
      const float4 a1 = *(const float4*)&As[kk][(64 + ty * 4) ^ swk];
      const float4 w0 = *(const float4*)&Ws[kk][(tx * 4) ^ swk];
      const float4 w1 = *(const float4*)&Ws[kk][(64 + tx * 4) ^ swk];
      const float av[8] = {a0.x, a0.y, a0.z, a0.w, a1.x, a1.y, a1.z, a1.w};
      const float wv[8] = {w0.x, w0.y, w0.z, w0.w, w1.x, w1.y, w1.z, w1.w};
#pragma unroll
      for (int i = 0; i < 8; ++i)
#pragma unroll
        for (int j = 0; j < 8; ++j) acc[i][j] += av[i] * wv[j];
    }
  }
#undef ISSUE_LOADS

  // ---- fused LSTM epilogue (unchanged math/order from round 3) ----
  const int myjl = (tx & 7) * 4;
  const int jbase = (bx << 5) + myjl;       // rnn col 0..508
  const int g0 = (tx < 8) ? 0 : 1;
  const int g1 = g0 + 2;
  float bs0[4], bs1[4];
#pragma unroll
  for (int j = 0; j < 4; ++j) {
    bs0[j] = b1[g0 * RNN + jbase + j] + b2[g0 * RNN + jbase + j];
    bs1[j] = b1[g1 * RNN + jbase + j] + b2[g1 * RNN + jbase + j];
  }
  const bool low = (tx < 8);
#pragma unroll
  for (int i = 0; i < 8; ++i) {
    float v0[4], v1[4], p0[4], p1[4];
#pragma unroll
    for (int j = 0; j < 4; ++j) {
      v0[j] = acc[i][j] + bs0[j];
      v1[j] = acc[i][4 + j] + bs1[j];
      p0[j] = __shfl_xor(v0[j], 8);
      p1[j] = __shfl_xor(v1[j], 8);
    }
    const bool mine = low ? (i < 4) : (i >= 4);
    if (mine) {
      const int row = rowBase + (low ? (ty * 4 + i) : (64 + ty * 4 + (i - 4)));
      const size_t off = (size_t)row * RNN + jbase;
      const float4 cold = *(const float4*)&c_io[off];
      const float co[4] = {cold.x, cold.y, cold.z, cold.w};
      float cn[4], hn[4];
#pragma unroll
      for (int j = 0; j < 4; ++j) {
        const float fi = low ? v0[j] : p0[j];
        const float fg = low ? v1[j] : p1[j];
        const float ff = low ? p0[j] : v0[j];
        const float fo = low ? p1[j] : v1[j];
        const float c2 = sigmoidf_(ff) * co[j] + sigmoidf_(fi) * tanhf(fg);
        cn[j] = c2;
        hn[j] = sigmoidf_(fo) * tanhf(c2);
      }
      *(float4*)&c_io[off] = make_float4(cn[0], cn[1], cn[2], cn[3]);
      *(float4*)&h_out[off] = make_float4(hn[0], hn[1], hn[2], hn[3]);
    }
  }
}

// -------- head: logits -> +gumbel -> softmax -> hard argmax -> angle ----------
// 16 batch rows per block; W_angle staged once into LDS (float4-XOR swizzle
// k4 ^ (d&7) -> conflict-optimal b128 reads); h rows are wave-uniform reads.
#define HROWS 16

__global__ __launch_bounds__(256) void head_kernel(
    const float* __restrict__ h1, const float* __restrict__ Wang,
    const float* __restrict__ bang, float* __restrict__ angle,
    float* __restrict__ out, int s) {
  __shared__ __align__(16) float4 Wl[DISC * 128];  // 128 KB
  const int tid = threadIdx.x;
  for (int u = tid; u < DISC * 128; u += 256) {
    const int d = u >> 7, k4 = u & 127;
    Wl[(d << 7) | (k4 ^ (d & 7))] =
        *(const float4*)&Wang[((size_t)d << 9) + (k4 << 2)];
  }
  __syncthreads();
  const int wave = tid >> 6;
  const int d = tid & 63;
  const int dsw = d & 7;
  const float bd = bang[d];
  const int rowBase = blockIdx.x * HROWS + wave * 4;
#pragma unroll 1
  for (int rr = 0; rr < 4; ++rr) {
    const int b = rowBase + rr;
    const float4* __restrict__ hr = (const float4*)(h1 + ((size_t)b << 9));
    float acc = 0.f;
#pragma unroll 16
    for (int k4 = 0; k4 < 128; ++k4) {
      const float4 a = hr[k4];
      const float4 w = Wl[(d << 7) | (k4 ^ dsw)];
      acc += a.x * w.x; acc += a.y * w.y; acc += a.z * w.z; acc += a.w * w.w;
    }
    float z = acc + bd;
    const uint32_t n = ((uint32_t)s * BATCH + (uint32_t)b) * DISC + (uint32_t)d;
    const uint32_t bits = threefry_bits(n);
    const float f = __uint_as_float((bits >> 9) | 0x3f800000u) - 1.0f;
    const float u = fmaxf(1e-8f, f + 1e-8f);
    const float gum = -logf(-logf(u));
    z += gum;
    float m = z;
#pragma unroll
    for (int off = 32; off; off >>= 1) m = fmaxf(m, __shfl_xor(m, off));
    const float e = expf(z - m);
    float ssum = e;
#pragma unroll
    for (int off = 32; off; off >>= 1) ssum += __shfl_xor(ssum, off);
    const float y = e / ssum;
    float ymax = y;
#pragma unroll
    for (int off = 32; off; off >>= 1) ymax = fmaxf(ymax, __shfl_xor(ymax, off));
    const unsigned long long mask = __ballot(y == ymax);
    const int k = __ffsll(mask) - 1;
    if (d == 0) {
      const float sp = -1.0f + (2.0f / 63.0f) * (float)k;  // linspace(-1,1,64)[k]
      angle[b] = sp;
      out[((size_t)b * NSEG + s) * 2 + 0] = sp;
      out[((size_t)b * NSEG + s) * 2 + 1] = 0.0f;
    }
  }
}

// ------------------------------- launch ---------------------------------------
extern "C" void kernel_launch(void* const* d_in, const int* in_sizes, int n_in,
                              void* d_out, int out_size, void* d_ws, size_t ws_size,
                              hipStream_t stream) {
  const float* latent   = (const float*)d_in[0];
  const float* W_unpack = (const float*)d_in[1];
  const float* b_unpack = (const float*)d_in[2];
  const float* Wih0     = (const float*)d_in[3];
  const float* Whh0     = (const float*)d_in[4];
  const float* bih0     = (const float*)d_in[5];
  const float* bhh0     = (const float*)d_in[6];
  const float* Wih1     = (const float*)d_in[7];
  const float* Whh1     = (const float*)d_in[8];
  const float* bih1     = (const float*)d_in[9];
  const float* bhh1     = (const float*)d_in[10];
  const float* W_angle  = (const float*)d_in[11];
  const float* b_angle  = (const float*)d_in[12];
  float* out = (float*)d_out;

  const size_t HC = (size_t)BATCH * RNN;  // 2M floats
  float* ws    = (float*)d_ws;
  float* h0a   = ws;
  float* h1a   = h0a + HC;
  float* c0    = h1a + HC;
  float* c1    = c0 + HC;
  float* angle = c1 + HC;                 // BATCH floats
  float* h0b   = angle + BATCH;
  float* h1b   = h0b + HC;
  float* x     = h1b + HC;
  float* base  = x + (size_t)BATCH * CODE;

  // zero the step-0-read state: h0a, h1a, c0, c1, angle (contiguous)
  hipMemsetAsync(ws, 0, (4 * HC + BATCH) * sizeof(float), stream);

  base_kernel<<<BATCH, 256, 0, stream>>>(latent, W_unpack, b_unpack, base);

  dim3 ggrid(16, 32);
  for (int s = 0; s < NSEG; ++s) {
    const int p = s & 1;
    float* h0p = p ? h0b : h0a; float* h0n = p ? h0a : h0b;
    float* h1p = p ? h1b : h1a; float* h1n = p ? h1a : h1b;
    x_kernel<<<(BATCH * CODE) / 256, 256, 0, stream>>>(base, angle, W_unpack, x);
    gemm_lstm<<<ggrid, 256, 0, stream>>>(x, Wih0, h0p, Whh0, bih0, bhh0, c0, h0n);
    gemm_lstm<<<ggrid, 256, 0, stream>>>(h0n, Wih1, h1p, Whh1, bih1, bhh1, c1, h1n);
    head_kernel<<<BATCH / HROWS, 256, 0, stream>>>(h1n, W_angle, b_angle, angle, out, s);
  }
}

// Round 5
// 34594.290 us; speedup vs baseline: 1.3208x; 1.3208x over previous
//
#include <hip/hip_runtime.h>
#include <cstdint>

#define BATCH 4096
#define LATENT 128
#define RNN 512
#define CODE 512
#define DISC 64
#define NSEG 64
#define UNPACK_COLS 130  // LATENT + INPUT

// ------------- threefry2x32, JAX partitionable mode, key = (0, 42) -----------
__device__ __forceinline__ uint32_t rotl32(uint32_t x, uint32_t r) {
  return (x << r) | (x >> (32u - r));
}

__device__ __forceinline__ uint32_t threefry_bits(uint32_t n) {
  const uint32_t k0 = 0u, k1 = 42u;
  const uint32_t ks2 = k0 ^ k1 ^ 0x1BD11BDAu;
  uint32_t x0 = 0u, x1 = n;
  x0 += k0; x1 += k1;
#define TF_ROUND(r) { x0 += x1; x1 = rotl32(x1, r); x1 ^= x0; }
  TF_ROUND(13) TF_ROUND(15) TF_ROUND(26) TF_ROUND(6)
  x0 += k1;  x1 += ks2 + 1u;
  TF_ROUND(17) TF_ROUND(29) TF_ROUND(16) TF_ROUND(24)
  x0 += ks2; x1 += k0 + 2u;
  TF_ROUND(13) TF_ROUND(15) TF_ROUND(26) TF_ROUND(6)
  x0 += k0;  x1 += k1 + 3u;
  TF_ROUND(17) TF_ROUND(29) TF_ROUND(16) TF_ROUND(24)
  x0 += k1;  x1 += ks2 + 4u;
  TF_ROUND(13) TF_ROUND(15) TF_ROUND(26) TF_ROUND(6)
  x0 += ks2; x1 += k0 + 5u;
#undef TF_ROUND
  return x0 ^ x1;
}

__device__ __forceinline__ float sigmoidf_(float v) {
  return 1.0f / (1.0f + expf(-v));
}

// ---------------- base = latent @ W_unpack[:, :128]^T + b_unpack --------------
__global__ __launch_bounds__(256) void base_kernel(
    const float* __restrict__ latent, const float* __restrict__ Wu,
    const float* __restrict__ bu, float* __restrict__ base) {
  __shared__ float lrow[LATENT];
  const int b = blockIdx.x;
  if (threadIdx.x < LATENT) lrow[threadIdx.x] = latent[b * LATENT + threadIdx.x];
  __syncthreads();
  for (int n = threadIdx.x; n < CODE; n += 256) {
    const float* wr = Wu + (size_t)n * UNPACK_COLS;
    float acc = 0.f;
#pragma unroll 8
    for (int k = 0; k < LATENT; ++k) acc += lrow[k] * wr[k];
    base[(size_t)b * CODE + n] = acc + bu[n];
  }
}

// ---------------- x = tanh(base + angle * W_unpack[:, 128]) -------------------
__global__ __launch_bounds__(256) void x_kernel(
    const float* __restrict__ base, const float* __restrict__ angle,
    const float* __restrict__ Wu, float* __restrict__ xo) {
  const int idx = blockIdx.x * 256 + threadIdx.x;
  const int b = idx >> 9;
  const int n = idx & 511;
  xo[idx] = tanhf(base[idx] + angle[b] * Wu[(size_t)n * UNPACK_COLS + 128]);
}

// ----- fused: gates = A1@W1^T + A2@W2^T + b1 + b2 ; (h,c) = LSTM(gates, c) ----
// global_load_lds double-buffered pipeline (T3/T4): loads for step s+1 issued
// before compute of step s, counted vmcnt(4), raw asm barriers.  LDS tiles are
// row-major [128 rows][16 k] with k-chunk XOR swizzle pos = k4 ^ ((row>>2)&3)
// applied via pre-swizzled per-lane GLOBAL source (linear LDS dest).
// Per 4-k chunk: 16x ds_read_b128 fragments, 256 FMAs, k strictly ascending
// (bit-identical accumulation order to prior rounds).
#define BM 128
#define BK 16
#define KSTEPS 64  // 2 segs * (512/16)

__global__ __launch_bounds__(256) void gemm_lstm(
    const float* __restrict__ A1, const float* __restrict__ W1,
    const float* __restrict__ A2, const float* __restrict__ W2,
    const float* __restrict__ b1, const float* __restrict__ b2,
    float* __restrict__ c_io, float* __restrict__ h_out) {
  __shared__ __align__(16) float As[2 * 2048];  // 2 bufs x [128][16]
  __shared__ __align__(16) float Ws[2 * 2048];
  const int tid = threadIdx.x;
  const int tx = tid & 15, ty = tid >> 4;       // ty in [0,16)
  const int bx = blockIdx.x;                    // 16 N-tiles (4 gates x 32 cols)
  const int rowBase = blockIdx.y * BM;
  const int wave = tid >> 6;
  const int lane = tid & 63;

  // Fill mapping: wave w fills chunks {2w, 2w+1}; chunk c = rows [16c,16c+16).
  // Lane l writes 16B at chunk_base + l*16 = (row = 16c + l/4, pos = l&3).
  // Stored pos holds global k-chunk  kch = pos ^ ((row>>2)&3).
  int aoff[2], woff[2], ldsc[2];
#pragma unroll
  for (int r = 0; r < 2; ++r) {
    const int c = 2 * wave + r;
    const int n = 16 * c + (lane >> 2);
    const int kch = (lane & 3) ^ ((n >> 2) & 3);
    aoff[r] = (rowBase + n) * RNN + kch * 4;
    const int wn = ((n >> 5) * RNN) + (bx << 5) + (n & 31);  // gate-tiled W row
    woff[r] = wn * RNN + kch * 4;
    ldsc[r] = c * 256;  // float offset of chunk base within a buffer
  }

  float acc[8][8];
#pragma unroll
  for (int i = 0; i < 8; ++i)
#pragma unroll
    for (int j = 0; j < 8; ++j) acc[i][j] = 0.f;

#define ISSUE(step, buf)                                                       \
  {                                                                            \
    const float* __restrict__ A_ = ((step) & 32) ? A2 : A1;                    \
    const float* __restrict__ W_ = ((step) & 32) ? W2 : W1;                    \
    const int k0_ = ((step) & 31) * BK;                                        \
    _Pragma("unroll") for (int r = 0; r < 2; ++r) {                            \
      __builtin_amdgcn_global_load_lds(                                        \
          (const __attribute__((address_space(1))) void*)(A_ + aoff[r] + k0_), \
          (__attribute__((address_space(3))) void*)&As[(buf)*2048 + ldsc[r]],  \
          16, 0, 0);                                                           \
      __builtin_amdgcn_global_load_lds(                                        \
          (const __attribute__((address_space(1))) void*)(W_ + woff[r] + k0_), \
          (__attribute__((address_space(3))) void*)&Ws[(buf)*2048 + ldsc[r]],  \
          16, 0, 0);                                                           \
    }                                                                          \
  }

  ISSUE(0, 0)

  for (int s = 0; s < KSTEPS; ++s) {
    const int cur = s & 1;
    asm volatile("s_barrier" ::: "memory");  // prev compute done; buf cur^1 free
    if (s + 1 < KSTEPS) {
      ISSUE(s + 1, cur ^ 1)
      asm volatile("s_waitcnt vmcnt(4)" ::: "memory");  // step-s data arrived
    } else {
      asm volatile("s_waitcnt vmcnt(0)" ::: "memory");
    }
    asm volatile("s_barrier" ::: "memory");  // all waves' step-s data visible

    const float* as_ = &As[cur * 2048];
    const float* ws_ = &Ws[cur * 2048];
#pragma unroll
    for (int c4 = 0; c4 < 4; ++c4) {
      float4 af[8], wf[8];
#pragma unroll
      for (int i = 0; i < 4; ++i) {
        const int m0 = ty * 4 + i, m1 = 64 + ty * 4 + i;
        af[i]     = *(const float4*)&as_[m0 * 16 + ((c4 ^ ((m0 >> 2) & 3)) << 2)];
        af[i + 4] = *(const float4*)&as_[m1 * 16 + ((c4 ^ ((m1 >> 2) & 3)) << 2)];
      }
#pragma unroll
      for (int j = 0; j < 8; ++j) {
        const int n = tx + 16 * j;  // strided cols: all 4 gates land per thread
        wf[j] = *(const float4*)&ws_[n * 16 + ((c4 ^ ((n >> 2) & 3)) << 2)];
      }
#pragma unroll
      for (int kk = 0; kk < 4; ++kk) {
#pragma unroll
        for (int i = 0; i < 8; ++i) {
          const float a = ((const float*)&af[i])[kk];
#pragma unroll
          for (int j = 0; j < 8; ++j)
            acc[i][j] += a * ((const float*)&wf[j])[kk];
        }
      }
    }
  }
#undef ISSUE

  // ---- fused LSTM epilogue: acc[i][j] = (gate j>>1, colpair j&1) ----
  const int col0 = (bx << 5) + tx;
  float bsum[8];
#pragma unroll
  for (int j = 0; j < 8; ++j) {
    const int g = j >> 1, cj = j & 1;
    bsum[j] = b1[g * RNN + col0 + 16 * cj] + b2[g * RNN + col0 + 16 * cj];
  }
#pragma unroll
  for (int i = 0; i < 8; ++i) {
    const int mrow = rowBase + ((i < 4) ? (ty * 4 + i) : (60 + ty * 4 + i));
#pragma unroll
    for (int cj = 0; cj < 2; ++cj) {
      const size_t off = (size_t)mrow * RNN + col0 + 16 * cj;
      const float gi = acc[i][0 + cj] + bsum[0 + cj];
      const float gf = acc[i][2 + cj] + bsum[2 + cj];
      const float gg = acc[i][4 + cj] + bsum[4 + cj];
      const float go = acc[i][6 + cj] + bsum[6 + cj];
      const float cold = c_io[off];
      const float cn = sigmoidf_(gf) * cold + sigmoidf_(gi) * tanhf(gg);
      c_io[off] = cn;
      h_out[off] = sigmoidf_(go) * tanhf(cn);
    }
  }
}

// -------- head: logits -> +gumbel -> softmax -> hard argmax -> angle ----------
#define HROWS 16

__global__ __launch_bounds__(256) void head_kernel(
    const float* __restrict__ h1, const float* __restrict__ Wang,
    const float* __restrict__ bang, float* __restrict__ angle,
    float* __restrict__ out, int s) {
  __shared__ __align__(16) float4 Wl[DISC * 128];  // 128 KB
  const int tid = threadIdx.x;
  for (int u = tid; u < DISC * 128; u += 256) {
    const int d = u >> 7, k4 = u & 127;
    Wl[(d << 7) | (k4 ^ (d & 7))] =
        *(const float4*)&Wang[((size_t)d << 9) + (k4 << 2)];
  }
  __syncthreads();
  const int wave = tid >> 6;
  const int d = tid & 63;
  const int dsw = d & 7;
  const float bd = bang[d];
  const int rowBase = blockIdx.x * HROWS + wave * 4;
#pragma unroll 1
  for (int rr = 0; rr < 4; ++rr) {
    const int b = rowBase + rr;
    const float4* __restrict__ hr = (const float4*)(h1 + ((size_t)b << 9));
    float acc = 0.f;
#pragma unroll 16
    for (int k4 = 0; k4 < 128; ++k4) {
      const float4 a = hr[k4];
      const float4 w = Wl[(d << 7) | (k4 ^ dsw)];
      acc += a.x * w.x; acc += a.y * w.y; acc += a.z * w.z; acc += a.w * w.w;
    }
    float z = acc + bd;
    const uint32_t n = ((uint32_t)s * BATCH + (uint32_t)b) * DISC + (uint32_t)d;
    const uint32_t bits = threefry_bits(n);
    const float f = __uint_as_float((bits >> 9) | 0x3f800000u) - 1.0f;
    const float u = fmaxf(1e-8f, f + 1e-8f);
    const float gum = -logf(-logf(u));
    z += gum;
    float m = z;
#pragma unroll
    for (int off = 32; off; off >>= 1) m = fmaxf(m, __shfl_xor(m, off));
    const float e = expf(z - m);
    float ssum = e;
#pragma unroll
    for (int off = 32; off; off >>= 1) ssum += __shfl_xor(ssum, off);
    const float y = e / ssum;
    float ymax = y;
#pragma unroll
    for (int off = 32; off; off >>= 1) ymax = fmaxf(ymax, __shfl_xor(ymax, off));
    const unsigned long long mask = __ballot(y == ymax);
    const int k = __ffsll(mask) - 1;
    if (d == 0) {
      const float sp = -1.0f + (2.0f / 63.0f) * (float)k;  // linspace(-1,1,64)[k]
      angle[b] = sp;
      out[((size_t)b * NSEG + s) * 2 + 0] = sp;
      out[((size_t)b * NSEG + s) * 2 + 1] = 0.0f;
    }
  }
}

// ------------------------------- launch ---------------------------------------
extern "C" void kernel_launch(void* const* d_in, const int* in_sizes, int n_in,
                              void* d_out, int out_size, void* d_ws, size_t ws_size,
                              hipStream_t stream) {
  const float* latent   = (const float*)d_in[0];
  const float* W_unpack = (const float*)d_in[1];
  const float* b_unpack = (const float*)d_in[2];
  const float* Wih0     = (const float*)d_in[3];
  const float* Whh0     = (const float*)d_in[4];
  const float* bih0     = (const float*)d_in[5];
  const float* bhh0     = (const float*)d_in[6];
  const float* Wih1     = (const float*)d_in[7];
  const float* Whh1     = (const float*)d_in[8];
  const float* bih1     = (const float*)d_in[9];
  const float* bhh1     = (const float*)d_in[10];
  const float* W_angle  = (const float*)d_in[11];
  const float* b_angle  = (const float*)d_in[12];
  float* out = (float*)d_out;

  const size_t HC = (size_t)BATCH * RNN;  // 2M floats
  float* ws    = (float*)d_ws;
  float* h0a   = ws;
  float* h1a   = h0a + HC;
  float* c0    = h1a + HC;
  float* c1    = c0 + HC;
  float* angle = c1 + HC;                 // BATCH floats
  float* h0b   = angle + BATCH;
  float* h1b   = h0b + HC;
  float* x     = h1b + HC;
  float* base  = x + (size_t)BATCH * CODE;

  // zero the step-0-read state: h0a, h1a, c0, c1, angle (contiguous)
  hipMemsetAsync(ws, 0, (4 * HC + BATCH) * sizeof(float), stream);

  base_kernel<<<BATCH, 256, 0, stream>>>(latent, W_unpack, b_unpack, base);

  dim3 ggrid(16, 32);
  for (int s = 0; s < NSEG; ++s) {
    const int p = s & 1;
    float* h0p = p ? h0b : h0a; float* h0n = p ? h0a : h0b;
    float* h1p = p ? h1b : h1a; float* h1n = p ? h1a : h1b;
    x_kernel<<<(BATCH * CODE) / 256, 256, 0, stream>>>(base, angle, W_unpack, x);
    gemm_lstm<<<ggrid, 256, 0, stream>>>(x, Wih0, h0p, Whh0, bih0, bhh0, c0, h0n);
    gemm_lstm<<<ggrid, 256, 0, stream>>>(h0n, Wih1, h1p, Whh1, bih1, bhh1, c1, h1n);
    head_kernel<<<BATCH / HROWS, 256, 0, stream>>>(h1n, W_angle, b_angle, angle, out, s);
  }
}